// Round 7
// baseline (156.016 us; speedup 1.0000x reference)
//
#include <hip/hip_runtime.h>
#include <hip/hip_bf16.h>

typedef __attribute__((ext_vector_type(8))) short bf16x8;
typedef __attribute__((ext_vector_type(4))) float floatx4;

#define B_TOT 4096
#define NKEEP 25
#define DIM 128
#define SCALE_Q 0.17677669529663687f

#define NCB  (262144)    // 64 g * 4 h * 16 grp * 64 lane
#define NW1  (6144)      // 24 ot * 4 kk * 64 lane
#define NW2  (2048)      // 8 ot * 4 kk * 64 lane

__device__ __forceinline__ short f2bs(float f) {
  __hip_bfloat16 h = __float2bfloat16(f);
  return *reinterpret_cast<short*>(&h);
}

// XB bank-conflict swizzle: fold the per-lane-varying bits 5-7 into the
// bank-group bits 0-2. Bijective involution; applied on BOTH sides.
__device__ __forceinline__ int swz(int u) { return u ^ ((u >> 5) & 7); }

__device__ __forceinline__ bf16x8 ld8(const float* p) {
  const float4 u = reinterpret_cast<const float4*>(p)[0];
  const float4 v = reinterpret_cast<const float4*>(p)[1];
  bf16x8 r;
  r[0] = f2bs(u.x); r[1] = f2bs(u.y); r[2] = f2bs(u.z); r[3] = f2bs(u.w);
  r[4] = f2bs(v.x); r[5] = f2bs(v.y); r[6] = f2bs(v.z); r[7] = f2bs(v.w);
  return r;
}

// ---------------- k_prep: combs + weight fragments only ----------
// combs layout matches the SWAPPED-S lane mapping in k_fused:
// (m = mt*16 + l16, n = nt*16 + quad*4 + rr).
__global__ __launch_bounds__(256) void k_prep(
    const float* __restrict__ w1, const float* __restrict__ w2,
    const float* __restrict__ mask, const int* __restrict__ ids,
    const int* __restrict__ rel, const float* __restrict__ btab,
    short* __restrict__ w1s, short* __restrict__ w2s,
    float* __restrict__ combs)
{
  const int t = blockIdx.x * 256 + threadIdx.x;
  if (t < NCB) {
    const int g = t >> 12, rest = t & 4095;
    const int h = rest >> 10, j = rest & 1023;
    const int grp = j >> 6, lane = j & 63;
    const int mt = grp >> 3, nt = (grp >> 2) & 1, rr = grp & 3;
    const int quad = lane >> 4, l16 = lane & 15;
    const int m = mt * 16 + l16, n = nt * 16 + quad * 4 + rr;   // swapped-S map
    float v = 0.f;
    if (m < 25 && n < 25) {
      const int im = ids[g * 25 + m], in = ids[g * 25 + n];
      v = btab[rel[im * 49 + in] * 4 + h] + mask[((size_t)g * 49 + im) * 49 + in];
    }
    combs[t] = v;
  } else if (t < NCB + NW1) {
    const int c = t - NCB;
    const int ot = c >> 8, rem = c & 255, kk = rem >> 6, l = rem & 63;
    const int quad = l >> 4, l16 = l & 15;
    *reinterpret_cast<bf16x8*>(w1s + (size_t)c * 8) =
        ld8(w1 + (size_t)(ot * 16 + l16) * DIM + kk * 32 + quad * 8);
  } else {
    const int c = t - (NCB + NW1);
    const int ot = c >> 8, rem = c & 255, kk = rem >> 6, l = rem & 63;
    const int quad = l >> 4, l16 = l & 15;
    *reinterpret_cast<bf16x8*>(w2s + (size_t)c * 8) =
        ld8(w2 + (size_t)(ot * 16 + l16) * DIM + kk * 32 + quad * 8);
  }
}

// ---------------- k_fused -------------------------------------------------
// R6 base (swapped Q/K/O producers, packed short4 epilogues) with ONE fix:
// w2f (proj weights, 32 regs) is loaded AT the proj site, after barrier2.
// The compiler cannot hoist a global load back across __syncthreads, so the
// QKV/attention phase's peak register liveness drops ~32 regs below R6
// (and ~20 below R5's proven-safe level) -> no scratch spill. w2s is 32 KB
// and read every round by every block -> permanently L2-hot; its ~200cy
// latency at proj is covered by acc2 init + TL ds_reads.
__global__ __launch_bounds__(256, 2) void k_fused(
    const float* __restrict__ x, const short* __restrict__ w1s,
    const short* __restrict__ w2s, const float* __restrict__ qkvb,
    const float* __restrict__ pb, const float* __restrict__ combs,
    float* __restrict__ out)
{
  __shared__ __align__(16) short XB[8192];    // 2 x 512 units of 8 shorts
  __shared__ __align__(16) short TL[10240];   // 8 tiles of 32x40 shorts

  const int tid = threadIdx.x;
  const int wv = tid >> 6, l = tid & 63, l16 = l & 15, quad = l >> 4;
  const int h = wv;
  short* T1 = TL + wv * 2560;
  short* T2 = T1 + 1280;
  const int win0 = blockIdx.x * 4;
  const floatx4 zero = {0.f, 0.f, 0.f, 0.f};

  // staging geometry (uniform per thread across rounds)
  const int sr = tid >> 3, sc = tid & 7;
  const int smt = sr >> 4, sl = sr & 15, skk = sc >> 1, sq = (sc & 1) * 2;
  const int stok = (sr > 24) ? 24 : sr;
  const int ubase = (smt * 4 + skk) * 64 + sq * 16 + sl;  // 16B-unit index

  const int otl[6] = {2*h, 2*h+1, 8+2*h, 9+2*h, 16+2*h, 17+2*h};

  // persistent register weights + biases
  bf16x8 w1f[6][4];
#pragma unroll
  for (int t = 0; t < 6; ++t)
#pragma unroll
    for (int kk = 0; kk < 4; ++kk)
      w1f[t][kk] = *reinterpret_cast<const bf16x8*>(
          w1s + ((size_t)(otl[t] * 4 + kk) * 64 + l) * 8);
  // per-channel biases for swapped Q/K (channel = quad*4+rr within group t)
  float qbs[4][4];
#pragma unroll
  for (int t = 0; t < 4; ++t)
#pragma unroll
    for (int rr = 0; rr < 4; ++rr)
      qbs[t][rr] = qkvb[otl[t] * 16 + quad * 4 + rr];
  // per-l16 biases for unswapped V
  float qbv[2];
#pragma unroll
  for (int t = 0; t < 2; ++t) qbv[t] = qkvb[otl[4 + t] * 16 + l16];
  float pbf[2];
#pragma unroll
  for (int nt = 0; nt < 2; ++nt) pbf[nt] = pb[h * 32 + nt * 16 + l16];

  // stage window 0 into XB half 0
  {
    const float* p = x + (size_t)win0 * 3200 + stok * 128 + sc * 16;
    float4 f0 = reinterpret_cast<const float4*>(p)[0];
    float4 f1 = reinterpret_cast<const float4*>(p)[1];
    float4 f2 = reinterpret_cast<const float4*>(p)[2];
    float4 f3 = reinterpret_cast<const float4*>(p)[3];
    bf16x8 a, b;
    a[0] = f2bs(f0.x); a[1] = f2bs(f0.y); a[2] = f2bs(f0.z); a[3] = f2bs(f0.w);
    a[4] = f2bs(f1.x); a[5] = f2bs(f1.y); a[6] = f2bs(f1.z); a[7] = f2bs(f1.w);
    b[0] = f2bs(f2.x); b[1] = f2bs(f2.y); b[2] = f2bs(f2.z); b[3] = f2bs(f2.w);
    b[4] = f2bs(f3.x); b[5] = f2bs(f3.y); b[6] = f2bs(f3.z); b[7] = f2bs(f3.w);
    *reinterpret_cast<bf16x8*>(XB + swz(ubase) * 8) = a;
    *reinterpret_cast<bf16x8*>(XB + swz(ubase + 16) * 8) = b;
  }

  for (int r = 0; r < 4; ++r) {
    const int win = win0 + r;
    const int g = win & 63;

    __syncthreads();   // barrier 1: prev round's proj reads done; XB visible

    // ---- A fragments from XB first (LDS only) ----
    bf16x8 aW[2][4];
#pragma unroll
    for (int kk = 0; kk < 4; ++kk) {
      const int base = (r & 1) * 512;
      aW[0][kk] = *reinterpret_cast<const bf16x8*>(XB + swz(base + kk * 64 + l) * 8);
      aW[1][kk] = *reinterpret_cast<const bf16x8*>(XB + swz(base + (4 + kk) * 64 + l) * 8);
    }

    // ---- prefetches issued NOW (post-barrier): consumed much later ----
    float4 xf0, xf1, xf2, xf3;
    if (r < 3) {
      const float* p = x + (size_t)(win + 1) * 3200 + stok * 128 + sc * 16;
      xf0 = reinterpret_cast<const float4*>(p)[0];
      xf1 = reinterpret_cast<const float4*>(p)[1];
      xf2 = reinterpret_cast<const float4*>(p)[2];
      xf3 = reinterpret_cast<const float4*>(p)[3];
    }
    float cmb[2][2][4];
#pragma unroll
    for (int mt = 0; mt < 2; ++mt)
#pragma unroll
      for (int nt = 0; nt < 2; ++nt)
#pragma unroll
        for (int rr = 0; rr < 4; ++rr)
          cmb[mt][nt][rr] =
              combs[(((size_t)g * 4 + h) * 16 + mt * 8 + nt * 4 + rr) * 64 + l];

    // ---- QKV: Q,K SWAPPED (channels per lane), V normal (tokens per lane) --
    floatx4 accT[4][2];   // [t: Q0,Q1,K0,K1][mt]  D-row=channel, D-col=token
    floatx4 accV[2][2];   // [mt][vt]              D-row=token,   D-col=channel
#pragma unroll
    for (int t = 0; t < 4; ++t)
#pragma unroll
      for (int mt = 0; mt < 2; ++mt) accT[t][mt] = zero;
#pragma unroll
    for (int mt = 0; mt < 2; ++mt)
#pragma unroll
      for (int vt = 0; vt < 2; ++vt) accV[mt][vt] = zero;
    __builtin_amdgcn_s_setprio(1);
#pragma unroll
    for (int kk = 0; kk < 4; ++kk) {
#pragma unroll
      for (int t = 0; t < 4; ++t) {
        accT[t][0] = __builtin_amdgcn_mfma_f32_16x16x32_bf16(w1f[t][kk], aW[0][kk], accT[t][0], 0, 0, 0);
        accT[t][1] = __builtin_amdgcn_mfma_f32_16x16x32_bf16(w1f[t][kk], aW[1][kk], accT[t][1], 0, 0, 0);
      }
#pragma unroll
      for (int vt = 0; vt < 2; ++vt) {
        accV[0][vt] = __builtin_amdgcn_mfma_f32_16x16x32_bf16(aW[0][kk], w1f[4 + vt][kk], accV[0][vt], 0, 0, 0);
        accV[1][vt] = __builtin_amdgcn_mfma_f32_16x16x32_bf16(aW[1][kk], w1f[4 + vt][kk], accV[1][vt], 0, 0, 0);
      }
    }
    __builtin_amdgcn_s_setprio(0);

    // Q -> T1 [tok][d], K -> T2 [tok][d]: packed short4 along channels
#pragma unroll
    for (int t = 0; t < 2; ++t)
#pragma unroll
      for (int mt = 0; mt < 2; ++mt) {
        short4 pq, pk;
        pq.x = f2bs((accT[t][mt][0] + qbs[t][0]) * SCALE_Q);
        pq.y = f2bs((accT[t][mt][1] + qbs[t][1]) * SCALE_Q);
        pq.z = f2bs((accT[t][mt][2] + qbs[t][2]) * SCALE_Q);
        pq.w = f2bs((accT[t][mt][3] + qbs[t][3]) * SCALE_Q);
        pk.x = f2bs(accT[2 + t][mt][0] + qbs[2 + t][0]);
        pk.y = f2bs(accT[2 + t][mt][1] + qbs[2 + t][1]);
        pk.z = f2bs(accT[2 + t][mt][2] + qbs[2 + t][2]);
        pk.w = f2bs(accT[2 + t][mt][3] + qbs[2 + t][3]);
        const int row = (mt * 16 + l16) * 40 + t * 16 + quad * 4;
        *reinterpret_cast<short4*>(&T1[row]) = pq;
        *reinterpret_cast<short4*>(&T2[row]) = pk;
      }

    // ---- attention (wave-local), SWAPPED QK^T ----
    bf16x8 aq[2], bk[2];
#pragma unroll
    for (int t = 0; t < 2; ++t) {
      aq[t] = *reinterpret_cast<const bf16x8*>(&T1[(t * 16 + l16) * 40 + quad * 8]);
      bk[t] = *reinterpret_cast<const bf16x8*>(&T2[(t * 16 + l16) * 40 + quad * 8]);
    }
    // St[nt][mt][rr]: q = mt*16 + l16 (col), k = nt*16 + quad*4 + rr (row)
    floatx4 St[2][2];
#pragma unroll
    for (int nt = 0; nt < 2; ++nt)
#pragma unroll
      for (int mt = 0; mt < 2; ++mt)
        St[nt][mt] = __builtin_amdgcn_mfma_f32_16x16x32_bf16(bk[nt], aq[mt], zero, 0, 0, 0);

#pragma unroll
    for (int mt = 0; mt < 2; ++mt) {
      float v[2][4];
      float mx = -1e30f;
#pragma unroll
      for (int nt = 0; nt < 2; ++nt)
#pragma unroll
        for (int rr = 0; rr < 4; ++rr) {
          const int kidx = nt * 16 + quad * 4 + rr;
          v[nt][rr] = (kidx < 25) ? St[nt][mt][rr] + cmb[mt][nt][rr] : -1e30f;
          mx = fmaxf(mx, v[nt][rr]);
        }
      mx = fmaxf(mx, __shfl_xor(mx, 16));
      mx = fmaxf(mx, __shfl_xor(mx, 32));
      float e[2][4];
      float sm = 0.f;
#pragma unroll
      for (int nt = 0; nt < 2; ++nt)
#pragma unroll
        for (int rr = 0; rr < 4; ++rr) {
          e[nt][rr] = __expf(v[nt][rr] - mx);
          sm += e[nt][rr];
        }
      sm += __shfl_xor(sm, 16);
      sm += __shfl_xor(sm, 32);
      const float inv = 1.f / sm;
      // P[q = mt*16+l16][k = nt*16+quad*4 .. +3] packed (K tile consumed)
#pragma unroll
      for (int nt = 0; nt < 2; ++nt) {
        short4 pk;
        pk.x = f2bs(e[nt][0] * inv);
        pk.y = f2bs(e[nt][1] * inv);
        pk.z = f2bs(e[nt][2] * inv);
        pk.w = f2bs(e[nt][3] * inv);
        *reinterpret_cast<short4*>(&T2[(mt * 16 + l16) * 40 + nt * 16 + quad * 4]) = pk;
      }
    }
    // VT over Q in T1 (Q consumed): [d][tok], packed 4 tokens per store
#pragma unroll
    for (int vt = 0; vt < 2; ++vt)
#pragma unroll
      for (int mt = 0; mt < 2; ++mt) {
        short4 pk;
        pk.x = f2bs(accV[mt][vt][0] + qbv[vt]);
        pk.y = f2bs(accV[mt][vt][1] + qbv[vt]);
        pk.z = f2bs(accV[mt][vt][2] + qbv[vt]);
        pk.w = f2bs(accV[mt][vt][3] + qbv[vt]);
        *reinterpret_cast<short4*>(&T1[(vt * 16 + l16) * 40 + mt * 16 + quad * 4]) = pk;
      }
    bf16x8 ap[2], bv[2];
#pragma unroll
    for (int t = 0; t < 2; ++t) {
      ap[t] = *reinterpret_cast<const bf16x8*>(&T2[(t * 16 + l16) * 40 + quad * 8]);
      bv[t] = *reinterpret_cast<const bf16x8*>(&T1[(t * 16 + l16) * 40 + quad * 8]);
    }
    // SWAPPED PV: OT[nt][mt] -> D-row = d (nt*16+quad*4+rr), D-col = q-tok
    floatx4 OT[2][2];
#pragma unroll
    for (int nt = 0; nt < 2; ++nt)
#pragma unroll
      for (int mt = 0; mt < 2; ++mt)
        OT[nt][mt] = __builtin_amdgcn_mfma_f32_16x16x32_bf16(bv[nt], ap[mt], zero, 0, 0, 0);
    // O -> T1 [tok][d_local]: packed short4 along channels
#pragma unroll
    for (int mt = 0; mt < 2; ++mt)
#pragma unroll
      for (int nt = 0; nt < 2; ++nt) {
        short4 pk;
        pk.x = f2bs(OT[nt][mt][0]);
        pk.y = f2bs(OT[nt][mt][1]);
        pk.z = f2bs(OT[nt][mt][2]);
        pk.w = f2bs(OT[nt][mt][3]);
        *reinterpret_cast<short4*>(&T1[(mt * 16 + l16) * 40 + nt * 16 + quad * 4]) = pk;
      }

    // stage next window into the other XB half (fp32 -> bf16 here; the
    // vmcnt wait for xf* lands HERE, ~a full round after issue)
    if (r < 3) {
      bf16x8 a, b;
      a[0] = f2bs(xf0.x); a[1] = f2bs(xf0.y); a[2] = f2bs(xf0.z); a[3] = f2bs(xf0.w);
      a[4] = f2bs(xf1.x); a[5] = f2bs(xf1.y); a[6] = f2bs(xf1.z); a[7] = f2bs(xf1.w);
      b[0] = f2bs(xf2.x); b[1] = f2bs(xf2.y); b[2] = f2bs(xf2.z); b[3] = f2bs(xf2.w);
      b[4] = f2bs(xf3.x); b[5] = f2bs(xf3.y); b[6] = f2bs(xf3.z); b[7] = f2bs(xf3.w);
      const int off = ((r + 1) & 1) * 512;
      *reinterpret_cast<bf16x8*>(XB + swz(off + ubase) * 8) = a;
      *reinterpret_cast<bf16x8*>(XB + swz(off + ubase + 16) * 8) = b;
    }
    __syncthreads();   // barrier 2: all O tiles ready, XB staged

    // ---- proj: w2f loaded HERE (short liveness, can't be hoisted across
    // the barrier); wave h -> out cols [h*32, h*32+32) ----
    bf16x8 w2f[2][4];
#pragma unroll
    for (int nt = 0; nt < 2; ++nt)
#pragma unroll
      for (int kk = 0; kk < 4; ++kk)
        w2f[nt][kk] = *reinterpret_cast<const bf16x8*>(
            w2s + ((size_t)((h * 2 + nt) * 4 + kk) * 64 + l) * 8);
    floatx4 acc2[2][2];
#pragma unroll
    for (int mt = 0; mt < 2; ++mt)
#pragma unroll
      for (int nt = 0; nt < 2; ++nt) acc2[mt][nt] = zero;
    __builtin_amdgcn_s_setprio(1);
#pragma unroll
    for (int kk = 0; kk < 4; ++kk) {
      const bf16x8 a20 = *reinterpret_cast<const bf16x8*>(
          &TL[kk * 2560 + (l16) * 40 + quad * 8]);
      const bf16x8 a21 = *reinterpret_cast<const bf16x8*>(
          &TL[kk * 2560 + (16 + l16) * 40 + quad * 8]);
#pragma unroll
      for (int nt = 0; nt < 2; ++nt) {
        acc2[0][nt] = __builtin_amdgcn_mfma_f32_16x16x32_bf16(a20, w2f[nt][kk], acc2[0][nt], 0, 0, 0);
        acc2[1][nt] = __builtin_amdgcn_mfma_f32_16x16x32_bf16(a21, w2f[nt][kk], acc2[1][nt], 0, 0, 0);
      }
    }
    __builtin_amdgcn_s_setprio(0);
#pragma unroll
    for (int mt = 0; mt < 2; ++mt)
#pragma unroll
      for (int rr = 0; rr < 4; ++rr) {
        const int m = mt * 16 + quad * 4 + rr;
        if (m < 25) {
#pragma unroll
          for (int nt = 0; nt < 2; ++nt)
            out[((size_t)win * NKEEP + m) * DIM + h * 32 + nt * 16 + l16] =
                acc2[mt][nt][rr] + pbf[nt];
        }
      }
  }
}

extern "C" void kernel_launch(void* const* d_in, const int* in_sizes, int n_in,
                              void* d_out, int out_size, void* d_ws, size_t ws_size,
                              hipStream_t stream) {
  const float* x    = (const float*)d_in[0];
  const float* mask = (const float*)d_in[1];
  const int*   ids  = (const int*)d_in[2];
  const float* qkvw = (const float*)d_in[3];
  const float* qkvb = (const float*)d_in[4];
  const float* pw   = (const float*)d_in[5];
  const float* pb   = (const float*)d_in[6];
  const float* btab = (const float*)d_in[7];
  const int*   rel  = (const int*)d_in[8];

  short* w1s   = (short*)d_ws;                      // 96 KB
  short* w2s   = w1s + (size_t)NW1 * 8;             // 32 KB
  float* combs = (float*)(w2s + (size_t)NW2 * 8);   // 1 MB
  float* out   = (float*)d_out;

  k_prep <<<dim3((NCB + NW1 + NW2) / 256), 256, 0, stream>>>(
      qkvw, pw, mask, ids, rel, btab, w1s, w2s, combs);
  k_fused<<<dim3(B_TOT / 4), 256, 0, stream>>>(
      x, w1s, w2s, qkvb, pb, combs, out);
}

// Round 10
// 152.516 us; speedup vs baseline: 1.0229x; 1.0229x over previous
//
#include <hip/hip_runtime.h>
#include <hip/hip_bf16.h>

typedef __attribute__((ext_vector_type(8))) short bf16x8;
typedef __attribute__((ext_vector_type(4))) float floatx4;

#define B_TOT 4096
#define NKEEP 25
#define DIM 128
#define SCALE_Q 0.17677669529663687f

#define NCB  (262144)    // 64 g * 4 h * 16 grp * 64 lane
#define NW1  (6144)      // 24 ot * 4 kk * 64 lane
#define NW2  (2048)      // 8 ot * 4 kk * 64 lane

__device__ __forceinline__ short f2bs(float f) {
  __hip_bfloat16 h = __float2bfloat16(f);
  return *reinterpret_cast<short*>(&h);
}

// XB bank-conflict swizzle: fold the per-lane-varying bits 5-7 into the
// bank-group bits 0-2. Bijective involution; applied on BOTH sides.
__device__ __forceinline__ int swz(int u) { return u ^ ((u >> 5) & 7); }

__device__ __forceinline__ bf16x8 ld8(const float* p) {
  const float4 u = reinterpret_cast<const float4*>(p)[0];
  const float4 v = reinterpret_cast<const float4*>(p)[1];
  bf16x8 r;
  r[0] = f2bs(u.x); r[1] = f2bs(u.y); r[2] = f2bs(u.z); r[3] = f2bs(u.w);
  r[4] = f2bs(v.x); r[5] = f2bs(v.y); r[6] = f2bs(v.z); r[7] = f2bs(v.w);
  return r;
}

// ---------------- k_prep: combs + weight fragments only ----------
// combs layout matches the SWAPPED-S lane mapping in k_fused:
// (m = mt*16 + l16, n = nt*16 + quad*4 + rr).
__global__ __launch_bounds__(256) void k_prep(
    const float* __restrict__ w1, const float* __restrict__ w2,
    const float* __restrict__ mask, const int* __restrict__ ids,
    const int* __restrict__ rel, const float* __restrict__ btab,
    short* __restrict__ w1s, short* __restrict__ w2s,
    float* __restrict__ combs)
{
  const int t = blockIdx.x * 256 + threadIdx.x;
  if (t < NCB) {
    const int g = t >> 12, rest = t & 4095;
    const int h = rest >> 10, j = rest & 1023;
    const int grp = j >> 6, lane = j & 63;
    const int mt = grp >> 3, nt = (grp >> 2) & 1, rr = grp & 3;
    const int quad = lane >> 4, l16 = lane & 15;
    const int m = mt * 16 + l16, n = nt * 16 + quad * 4 + rr;   // swapped-S map
    float v = 0.f;
    if (m < 25 && n < 25) {
      const int im = ids[g * 25 + m], in = ids[g * 25 + n];
      v = btab[rel[im * 49 + in] * 4 + h] + mask[((size_t)g * 49 + im) * 49 + in];
    }
    combs[t] = v;
  } else if (t < NCB + NW1) {
    const int c = t - NCB;
    const int ot = c >> 8, rem = c & 255, kk = rem >> 6, l = rem & 63;
    const int quad = l >> 4, l16 = l & 15;
    *reinterpret_cast<bf16x8*>(w1s + (size_t)c * 8) =
        ld8(w1 + (size_t)(ot * 16 + l16) * DIM + kk * 32 + quad * 8);
  } else {
    const int c = t - (NCB + NW1);
    const int ot = c >> 8, rem = c & 255, kk = rem >> 6, l = rem & 63;
    const int quad = l >> 4, l16 = l & 15;
    *reinterpret_cast<bf16x8*>(w2s + (size_t)c * 8) =
        ld8(w2 + (size_t)(ot * 16 + l16) * DIM + kk * 32 + quad * 8);
  }
}

// ---------------- k_fused -------------------------------------------------
// R5 base (proven 46.4 us, zero spill) + two zero-register-delta edits:
// (1) SWAPPED PV: OT[nt][mt] = mfma(VT-frag, P-frag) -> lane holds 4
//     consecutive channels for one token; O-store = 4 packed short4
//     (was 16 scalar ds_write_b16). T1's consumed [tok][d] layout unchanged.
// (2) s_setprio(1) around QKV/proj MFMA clusters (per-head independent
//     waves between barriers: the regime where setprio pays).
// The R6/R7 Q/K producer swap is REVERTED (its 18 persistent bias regs
// caused ~5-reg scratch spill: +21 MB HBM writes, +14 us).
__global__ __launch_bounds__(256, 2) void k_fused(
    const float* __restrict__ x, const short* __restrict__ w1s,
    const short* __restrict__ w2s, const float* __restrict__ qkvb,
    const float* __restrict__ pb, const float* __restrict__ combs,
    float* __restrict__ out)
{
  __shared__ __align__(16) short XB[8192];    // 2 x 512 units of 8 shorts
  __shared__ __align__(16) short TL[10240];   // 8 tiles of 32x40 shorts

  const int tid = threadIdx.x;
  const int wv = tid >> 6, l = tid & 63, l16 = l & 15, quad = l >> 4;
  const int h = wv;
  short* T1 = TL + wv * 2560;
  short* T2 = T1 + 1280;
  const int win0 = blockIdx.x * 4;
  const floatx4 zero = {0.f, 0.f, 0.f, 0.f};

  // staging geometry (uniform per thread across rounds)
  const int sr = tid >> 3, sc = tid & 7;
  const int smt = sr >> 4, sl = sr & 15, skk = sc >> 1, sq = (sc & 1) * 2;
  const int stok = (sr > 24) ? 24 : sr;
  const int ubase = (smt * 4 + skk) * 64 + sq * 16 + sl;  // 16B-unit index

  const int otl[6] = {2*h, 2*h+1, 8+2*h, 9+2*h, 16+2*h, 17+2*h};

  // persistent register weights + biases
  bf16x8 w1f[6][4];
#pragma unroll
  for (int t = 0; t < 6; ++t)
#pragma unroll
    for (int kk = 0; kk < 4; ++kk)
      w1f[t][kk] = *reinterpret_cast<const bf16x8*>(
          w1s + ((size_t)(otl[t] * 4 + kk) * 64 + l) * 8);
  float qb6[6];
#pragma unroll
  for (int t = 0; t < 6; ++t) qb6[t] = qkvb[otl[t] * 16 + l16];
  float pbf[2];
#pragma unroll
  for (int nt = 0; nt < 2; ++nt) pbf[nt] = pb[h * 32 + nt * 16 + l16];

  // stage window 0 into XB half 0
  {
    const float* p = x + (size_t)win0 * 3200 + stok * 128 + sc * 16;
    float4 f0 = reinterpret_cast<const float4*>(p)[0];
    float4 f1 = reinterpret_cast<const float4*>(p)[1];
    float4 f2 = reinterpret_cast<const float4*>(p)[2];
    float4 f3 = reinterpret_cast<const float4*>(p)[3];
    bf16x8 a, b;
    a[0] = f2bs(f0.x); a[1] = f2bs(f0.y); a[2] = f2bs(f0.z); a[3] = f2bs(f0.w);
    a[4] = f2bs(f1.x); a[5] = f2bs(f1.y); a[6] = f2bs(f1.z); a[7] = f2bs(f1.w);
    b[0] = f2bs(f2.x); b[1] = f2bs(f2.y); b[2] = f2bs(f2.z); b[3] = f2bs(f2.w);
    b[4] = f2bs(f3.x); b[5] = f2bs(f3.y); b[6] = f2bs(f3.z); b[7] = f2bs(f3.w);
    *reinterpret_cast<bf16x8*>(XB + swz(ubase) * 8) = a;
    *reinterpret_cast<bf16x8*>(XB + swz(ubase + 16) * 8) = b;
  }

  for (int r = 0; r < 4; ++r) {
    const int win = win0 + r;
    const int g = win & 63;

    __syncthreads();   // barrier 1: prev round's proj reads done; XB visible

    // ---- A fragments from XB first (LDS only) ----
    bf16x8 aW[2][4];
#pragma unroll
    for (int kk = 0; kk < 4; ++kk) {
      const int base = (r & 1) * 512;
      aW[0][kk] = *reinterpret_cast<const bf16x8*>(XB + swz(base + kk * 64 + l) * 8);
      aW[1][kk] = *reinterpret_cast<const bf16x8*>(XB + swz(base + (4 + kk) * 64 + l) * 8);
    }

    // ---- prefetches issued NOW (post-barrier): consumed much later ----
    float4 xf0, xf1, xf2, xf3;
    if (r < 3) {
      const float* p = x + (size_t)(win + 1) * 3200 + stok * 128 + sc * 16;
      xf0 = reinterpret_cast<const float4*>(p)[0];
      xf1 = reinterpret_cast<const float4*>(p)[1];
      xf2 = reinterpret_cast<const float4*>(p)[2];
      xf3 = reinterpret_cast<const float4*>(p)[3];
    }
    bf16x8 w2f[2][4];
#pragma unroll
    for (int nt = 0; nt < 2; ++nt)
#pragma unroll
      for (int kk = 0; kk < 4; ++kk)
        w2f[nt][kk] = *reinterpret_cast<const bf16x8*>(
            w2s + ((size_t)((h * 2 + nt) * 4 + kk) * 64 + l) * 8);
    float cmb[2][2][4];
#pragma unroll
    for (int mt = 0; mt < 2; ++mt)
#pragma unroll
      for (int nt = 0; nt < 2; ++nt)
#pragma unroll
        for (int rr = 0; rr < 4; ++rr)
          cmb[mt][nt][rr] =
              combs[(((size_t)g * 4 + h) * 16 + mt * 8 + nt * 4 + rr) * 64 + l];

    // ---- QKV: A from XB (registers), B from registers ----
    floatx4 acc[2][6];
#pragma unroll
    for (int mt = 0; mt < 2; ++mt)
#pragma unroll
      for (int t = 0; t < 6; ++t) acc[mt][t] = zero;
    __builtin_amdgcn_s_setprio(1);
#pragma unroll
    for (int kk = 0; kk < 4; ++kk) {
#pragma unroll
      for (int t = 0; t < 6; ++t) {
        acc[0][t] = __builtin_amdgcn_mfma_f32_16x16x32_bf16(aW[0][kk], w1f[t][kk], acc[0][t], 0, 0, 0);
        acc[1][t] = __builtin_amdgcn_mfma_f32_16x16x32_bf16(aW[1][kk], w1f[t][kk], acc[1][t], 0, 0, 0);
      }
    }
    __builtin_amdgcn_s_setprio(0);
    // epilogue: Q -> T1 [tok][d], K -> T2 [tok][d], V kept in regs
    float vres[2][2][4];
#pragma unroll
    for (int t = 0; t < 2; ++t)
#pragma unroll
      for (int mt = 0; mt < 2; ++mt)
#pragma unroll
        for (int rr = 0; rr < 4; ++rr) {
          const int row = (mt * 16 + quad * 4 + rr) * 40 + t * 16 + l16;
          T1[row] = f2bs((acc[mt][t][rr] + qb6[t]) * SCALE_Q);
          T2[row] = f2bs(acc[mt][2 + t][rr] + qb6[2 + t]);
          vres[t][mt][rr] = acc[mt][4 + t][rr] + qb6[4 + t];
        }

    // ---- attention (wave-local), SWAPPED QK^T ----
    bf16x8 aq[2], bk[2];
#pragma unroll
    for (int t = 0; t < 2; ++t) {
      aq[t] = *reinterpret_cast<const bf16x8*>(&T1[(t * 16 + l16) * 40 + quad * 8]);
      bk[t] = *reinterpret_cast<const bf16x8*>(&T2[(t * 16 + l16) * 40 + quad * 8]);
    }
    // St[nt][mt][rr]: q = mt*16 + l16 (col), k = nt*16 + quad*4 + rr (row)
    floatx4 St[2][2];
#pragma unroll
    for (int nt = 0; nt < 2; ++nt)
#pragma unroll
      for (int mt = 0; mt < 2; ++mt)
        St[nt][mt] = __builtin_amdgcn_mfma_f32_16x16x32_bf16(bk[nt], aq[mt], zero, 0, 0, 0);

#pragma unroll
    for (int mt = 0; mt < 2; ++mt) {
      float v[2][4];
      float mx = -1e30f;
#pragma unroll
      for (int nt = 0; nt < 2; ++nt)
#pragma unroll
        for (int rr = 0; rr < 4; ++rr) {
          const int kidx = nt * 16 + quad * 4 + rr;
          v[nt][rr] = (kidx < 25) ? St[nt][mt][rr] + cmb[mt][nt][rr] : -1e30f;
          mx = fmaxf(mx, v[nt][rr]);
        }
      mx = fmaxf(mx, __shfl_xor(mx, 16));
      mx = fmaxf(mx, __shfl_xor(mx, 32));
      float e[2][4];
      float sm = 0.f;
#pragma unroll
      for (int nt = 0; nt < 2; ++nt)
#pragma unroll
        for (int rr = 0; rr < 4; ++rr) {
          e[nt][rr] = __expf(v[nt][rr] - mx);
          sm += e[nt][rr];
        }
      sm += __shfl_xor(sm, 16);
      sm += __shfl_xor(sm, 32);
      const float inv = 1.f / sm;
      // P[q = mt*16+l16][k = nt*16+quad*4 .. +3] packed (K tile consumed)
#pragma unroll
      for (int nt = 0; nt < 2; ++nt) {
        short4 pk;
        pk.x = f2bs(e[nt][0] * inv);
        pk.y = f2bs(e[nt][1] * inv);
        pk.z = f2bs(e[nt][2] * inv);
        pk.w = f2bs(e[nt][3] * inv);
        *reinterpret_cast<short4*>(&T2[(mt * 16 + l16) * 40 + nt * 16 + quad * 4]) = pk;
      }
    }
    // VT over Q in T1 (Q consumed): [d][tok], packed 4 tokens per store
#pragma unroll
    for (int t = 0; t < 2; ++t)
#pragma unroll
      for (int mt = 0; mt < 2; ++mt) {
        short4 pk;
        pk.x = f2bs(vres[t][mt][0]); pk.y = f2bs(vres[t][mt][1]);
        pk.z = f2bs(vres[t][mt][2]); pk.w = f2bs(vres[t][mt][3]);
        *reinterpret_cast<short4*>(&T1[(t * 16 + l16) * 40 + mt * 16 + quad * 4]) = pk;
      }
    bf16x8 ap[2], bv[2];
#pragma unroll
    for (int t = 0; t < 2; ++t) {
      ap[t] = *reinterpret_cast<const bf16x8*>(&T2[(t * 16 + l16) * 40 + quad * 8]);
      bv[t] = *reinterpret_cast<const bf16x8*>(&T1[(t * 16 + l16) * 40 + quad * 8]);
    }
    // SWAPPED PV: OT[nt][mt] -> lane(quad,l16), reg rr holds
    // O[q = mt*16+l16][d = nt*16+quad*4+rr]
    floatx4 OT[2][2];
#pragma unroll
    for (int nt = 0; nt < 2; ++nt)
#pragma unroll
      for (int mt = 0; mt < 2; ++mt)
        OT[nt][mt] = __builtin_amdgcn_mfma_f32_16x16x32_bf16(bv[nt], ap[mt], zero, 0, 0, 0);
    // O -> T1 [tok][d_local]: packed short4 along channels (4 stores)
#pragma unroll
    for (int mt = 0; mt < 2; ++mt)
#pragma unroll
      for (int nt = 0; nt < 2; ++nt) {
        short4 pk;
        pk.x = f2bs(OT[nt][mt][0]);
        pk.y = f2bs(OT[nt][mt][1]);
        pk.z = f2bs(OT[nt][mt][2]);
        pk.w = f2bs(OT[nt][mt][3]);
        *reinterpret_cast<short4*>(&T1[(mt * 16 + l16) * 40 + nt * 16 + quad * 4]) = pk;
      }

    // stage next window into the other XB half (fp32 -> bf16 here; the
    // vmcnt wait for xf* lands HERE, ~a full round after issue)
    if (r < 3) {
      bf16x8 a, b;
      a[0] = f2bs(xf0.x); a[1] = f2bs(xf0.y); a[2] = f2bs(xf0.z); a[3] = f2bs(xf0.w);
      a[4] = f2bs(xf1.x); a[5] = f2bs(xf1.y); a[6] = f2bs(xf1.z); a[7] = f2bs(xf1.w);
      b[0] = f2bs(xf2.x); b[1] = f2bs(xf2.y); b[2] = f2bs(xf2.z); b[3] = f2bs(xf2.w);
      b[4] = f2bs(xf3.x); b[5] = f2bs(xf3.y); b[6] = f2bs(xf3.z); b[7] = f2bs(xf3.w);
      const int off = ((r + 1) & 1) * 512;
      *reinterpret_cast<bf16x8*>(XB + swz(off + ubase) * 8) = a;
      *reinterpret_cast<bf16x8*>(XB + swz(off + ubase + 16) * 8) = b;
    }
    __syncthreads();   // barrier 2: all O tiles ready, XB staged

    // ---- proj: wave h -> out cols [h*32, h*32+32) ----
    floatx4 acc2[2][2];
#pragma unroll
    for (int mt = 0; mt < 2; ++mt)
#pragma unroll
      for (int nt = 0; nt < 2; ++nt) acc2[mt][nt] = zero;
    __builtin_amdgcn_s_setprio(1);
#pragma unroll
    for (int kk = 0; kk < 4; ++kk) {
      const bf16x8 a20 = *reinterpret_cast<const bf16x8*>(
          &TL[kk * 2560 + (l16) * 40 + quad * 8]);
      const bf16x8 a21 = *reinterpret_cast<const bf16x8*>(
          &TL[kk * 2560 + (16 + l16) * 40 + quad * 8]);
#pragma unroll
      for (int nt = 0; nt < 2; ++nt) {
        acc2[0][nt] = __builtin_amdgcn_mfma_f32_16x16x32_bf16(a20, w2f[nt][kk], acc2[0][nt], 0, 0, 0);
        acc2[1][nt] = __builtin_amdgcn_mfma_f32_16x16x32_bf16(a21, w2f[nt][kk], acc2[1][nt], 0, 0, 0);
      }
    }
    __builtin_amdgcn_s_setprio(0);
#pragma unroll
    for (int mt = 0; mt < 2; ++mt)
#pragma unroll
      for (int rr = 0; rr < 4; ++rr) {
        const int m = mt * 16 + quad * 4 + rr;
        if (m < 25) {
#pragma unroll
          for (int nt = 0; nt < 2; ++nt)
            out[((size_t)win * NKEEP + m) * DIM + h * 32 + nt * 16 + l16] =
                acc2[mt][nt][rr] + pbf[nt];
        }
      }
  }
}

extern "C" void kernel_launch(void* const* d_in, const int* in_sizes, int n_in,
                              void* d_out, int out_size, void* d_ws, size_t ws_size,
                              hipStream_t stream) {
  const float* x    = (const float*)d_in[0];
  const float* mask = (const float*)d_in[1];
  const int*   ids  = (const int*)d_in[2];
  const float* qkvw = (const float*)d_in[3];
  const float* qkvb = (const float*)d_in[4];
  const float* pw   = (const float*)d_in[5];
  const float* pb   = (const float*)d_in[6];
  const float* btab = (const float*)d_in[7];
  const int*   rel  = (const int*)d_in[8];

  short* w1s   = (short*)d_ws;                      // 96 KB
  short* w2s   = w1s + (size_t)NW1 * 8;             // 32 KB
  float* combs = (float*)(w2s + (size_t)NW2 * 8);   // 1 MB
  float* out   = (float*)d_out;

  k_prep <<<dim3((NCB + NW1 + NW2) / 256), 256, 0, stream>>>(
      qkvw, pw, mask, ids, rel, btab, w1s, w2s, combs);
  k_fused<<<dim3(B_TOT / 4), 256, 0, stream>>>(
      x, w1s, w2s, qkvb, pb, combs, out);
}

// Round 11
// 140.748 us; speedup vs baseline: 1.1085x; 1.0836x over previous
//
#include <hip/hip_runtime.h>
#include <hip/hip_bf16.h>

typedef __attribute__((ext_vector_type(8))) short bf16x8;
typedef __attribute__((ext_vector_type(4))) float floatx4;

#define B_TOT 4096
#define NKEEP 25
#define DIM 128
#define SCALE_Q 0.17677669529663687f

#define NCB  (262144)    // 64 g * 4 h * 16 grp * 64 lane
#define NW1  (6144)      // 24 ot * 4 kk * 64 lane
#define NW2  (2048)      // 8 ot * 4 kk * 64 lane

__device__ __forceinline__ short f2bs(float f) {
  __hip_bfloat16 h = __float2bfloat16(f);
  return *reinterpret_cast<short*>(&h);
}

// XB bank-conflict swizzle: fold the per-lane-varying bits 5-7 into the
// bank-group bits 0-2. Bijective; applied on BOTH write and read sides.
__device__ __forceinline__ int swz(int u) { return u ^ ((u >> 5) & 7); }

__device__ __forceinline__ bf16x8 ld8(const float* p) {
  const float4 u = reinterpret_cast<const float4*>(p)[0];
  const float4 v = reinterpret_cast<const float4*>(p)[1];
  bf16x8 r;
  r[0] = f2bs(u.x); r[1] = f2bs(u.y); r[2] = f2bs(u.z); r[3] = f2bs(u.w);
  r[4] = f2bs(v.x); r[5] = f2bs(v.y); r[6] = f2bs(v.z); r[7] = f2bs(v.w);
  return r;
}

// ---------------- k_prep: combs + weight fragments only ----------
// combs layout matches the SWAPPED-S lane mapping in k_fused:
// entry (g,h,grp=(mt,nt,rr),lane=(quad,l16)) holds bias+mask at
// (m = mt*16 + l16, n = nt*16 + quad*4 + rr).
__global__ __launch_bounds__(256) void k_prep(
    const float* __restrict__ w1, const float* __restrict__ w2,
    const float* __restrict__ mask, const int* __restrict__ ids,
    const int* __restrict__ rel, const float* __restrict__ btab,
    short* __restrict__ w1s, short* __restrict__ w2s,
    float* __restrict__ combs)
{
  const int t = blockIdx.x * 256 + threadIdx.x;
  if (t < NCB) {
    const int g = t >> 12, rest = t & 4095;
    const int h = rest >> 10, j = rest & 1023;
    const int grp = j >> 6, lane = j & 63;
    const int mt = grp >> 3, nt = (grp >> 2) & 1, rr = grp & 3;
    const int quad = lane >> 4, l16 = lane & 15;
    const int m = mt * 16 + l16, n = nt * 16 + quad * 4 + rr;   // swapped-S map
    float v = 0.f;
    if (m < 25 && n < 25) {
      const int im = ids[g * 25 + m], in = ids[g * 25 + n];
      v = btab[rel[im * 49 + in] * 4 + h] + mask[((size_t)g * 49 + im) * 49 + in];
    }
    combs[t] = v;
  } else if (t < NCB + NW1) {
    const int c = t - NCB;
    const int ot = c >> 8, rem = c & 255, kk = rem >> 6, l = rem & 63;
    const int quad = l >> 4, l16 = l & 15;
    *reinterpret_cast<bf16x8*>(w1s + (size_t)c * 8) =
        ld8(w1 + (size_t)(ot * 16 + l16) * DIM + kk * 32 + quad * 8);
  } else {
    const int c = t - (NCB + NW1);
    const int ot = c >> 8, rem = c & 255, kk = rem >> 6, l = rem & 63;
    const int quad = l >> 4, l16 = l & 15;
    *reinterpret_cast<bf16x8*>(w2s + (size_t)c * 8) =
        ld8(w2 + (size_t)(ot * 16 + l16) * DIM + kk * 32 + quad * 8);
  }
}

// ---------------- k_fused -------------------------------------------------
// R5 exactly (proven 46.4 us k_fused / 137.7 us total, zero spill).
// SWAPPED QK^T: St[nt][mt] = mfma(K-tile, Q-tile) -> lane (quad,l16) holds
// q-row q=mt*16+l16 with 8 k-values (nt,rr). Row softmax = 7 fmax + 2 shfl
// (+ 7 add + 2 shfl); one reciprocal per row; P stored as packed short4.
// Session ledger: every further edit tested (R6/R7 Q/K producer swap,
// R8/R10 O-swap + setprio) re-triggered allocator spill (+13..21 MB HBM
// writes, +10..15 us) at this 128 VGPR + 64 AGPR / (256,2) boundary.
__global__ __launch_bounds__(256, 2) void k_fused(
    const float* __restrict__ x, const short* __restrict__ w1s,
    const short* __restrict__ w2s, const float* __restrict__ qkvb,
    const float* __restrict__ pb, const float* __restrict__ combs,
    float* __restrict__ out)
{
  __shared__ __align__(16) short XB[8192];    // 2 x 512 units of 8 shorts
  __shared__ __align__(16) short TL[10240];   // 8 tiles of 32x40 shorts

  const int tid = threadIdx.x;
  const int wv = tid >> 6, l = tid & 63, l16 = l & 15, quad = l >> 4;
  const int h = wv;
  short* T1 = TL + wv * 2560;
  short* T2 = T1 + 1280;
  const int win0 = blockIdx.x * 4;
  const floatx4 zero = {0.f, 0.f, 0.f, 0.f};

  // staging geometry (uniform per thread across rounds)
  const int sr = tid >> 3, sc = tid & 7;
  const int smt = sr >> 4, sl = sr & 15, skk = sc >> 1, sq = (sc & 1) * 2;
  const int stok = (sr > 24) ? 24 : sr;
  const int ubase = (smt * 4 + skk) * 64 + sq * 16 + sl;  // 16B-unit index

  const int otl[6] = {2*h, 2*h+1, 8+2*h, 9+2*h, 16+2*h, 17+2*h};

  // persistent register weights + biases
  bf16x8 w1f[6][4];
#pragma unroll
  for (int t = 0; t < 6; ++t)
#pragma unroll
    for (int kk = 0; kk < 4; ++kk)
      w1f[t][kk] = *reinterpret_cast<const bf16x8*>(
          w1s + ((size_t)(otl[t] * 4 + kk) * 64 + l) * 8);
  float qb6[6];
#pragma unroll
  for (int t = 0; t < 6; ++t) qb6[t] = qkvb[otl[t] * 16 + l16];
  float pbf[2];
#pragma unroll
  for (int nt = 0; nt < 2; ++nt) pbf[nt] = pb[h * 32 + nt * 16 + l16];

  // stage window 0 into XB half 0
  {
    const float* p = x + (size_t)win0 * 3200 + stok * 128 + sc * 16;
    float4 f0 = reinterpret_cast<const float4*>(p)[0];
    float4 f1 = reinterpret_cast<const float4*>(p)[1];
    float4 f2 = reinterpret_cast<const float4*>(p)[2];
    float4 f3 = reinterpret_cast<const float4*>(p)[3];
    bf16x8 a, b;
    a[0] = f2bs(f0.x); a[1] = f2bs(f0.y); a[2] = f2bs(f0.z); a[3] = f2bs(f0.w);
    a[4] = f2bs(f1.x); a[5] = f2bs(f1.y); a[6] = f2bs(f1.z); a[7] = f2bs(f1.w);
    b[0] = f2bs(f2.x); b[1] = f2bs(f2.y); b[2] = f2bs(f2.z); b[3] = f2bs(f2.w);
    b[4] = f2bs(f3.x); b[5] = f2bs(f3.y); b[6] = f2bs(f3.z); b[7] = f2bs(f3.w);
    *reinterpret_cast<bf16x8*>(XB + swz(ubase) * 8) = a;
    *reinterpret_cast<bf16x8*>(XB + swz(ubase + 16) * 8) = b;
  }

  for (int r = 0; r < 4; ++r) {
    const int win = win0 + r;
    const int g = win & 63;

    __syncthreads();   // barrier 1: prev round's proj reads done; XB visible

    // ---- A fragments from XB first (LDS only) ----
    bf16x8 aW[2][4];
#pragma unroll
    for (int kk = 0; kk < 4; ++kk) {
      const int base = (r & 1) * 512;
      aW[0][kk] = *reinterpret_cast<const bf16x8*>(XB + swz(base + kk * 64 + l) * 8);
      aW[1][kk] = *reinterpret_cast<const bf16x8*>(XB + swz(base + (4 + kk) * 64 + l) * 8);
    }

    // ---- prefetches issued NOW (post-barrier): consumed much later ----
    float4 xf0, xf1, xf2, xf3;
    if (r < 3) {
      const float* p = x + (size_t)(win + 1) * 3200 + stok * 128 + sc * 16;
      xf0 = reinterpret_cast<const float4*>(p)[0];
      xf1 = reinterpret_cast<const float4*>(p)[1];
      xf2 = reinterpret_cast<const float4*>(p)[2];
      xf3 = reinterpret_cast<const float4*>(p)[3];
    }
    bf16x8 w2f[2][4];
#pragma unroll
    for (int nt = 0; nt < 2; ++nt)
#pragma unroll
      for (int kk = 0; kk < 4; ++kk)
        w2f[nt][kk] = *reinterpret_cast<const bf16x8*>(
            w2s + ((size_t)((h * 2 + nt) * 4 + kk) * 64 + l) * 8);
    float cmb[2][2][4];
#pragma unroll
    for (int mt = 0; mt < 2; ++mt)
#pragma unroll
      for (int nt = 0; nt < 2; ++nt)
#pragma unroll
        for (int rr = 0; rr < 4; ++rr)
          cmb[mt][nt][rr] =
              combs[(((size_t)g * 4 + h) * 16 + mt * 8 + nt * 4 + rr) * 64 + l];

    // ---- QKV: A from XB (registers), B from registers ----
    floatx4 acc[2][6];
#pragma unroll
    for (int mt = 0; mt < 2; ++mt)
#pragma unroll
      for (int t = 0; t < 6; ++t) acc[mt][t] = zero;
#pragma unroll
    for (int kk = 0; kk < 4; ++kk) {
#pragma unroll
      for (int t = 0; t < 6; ++t) {
        acc[0][t] = __builtin_amdgcn_mfma_f32_16x16x32_bf16(aW[0][kk], w1f[t][kk], acc[0][t], 0, 0, 0);
        acc[1][t] = __builtin_amdgcn_mfma_f32_16x16x32_bf16(aW[1][kk], w1f[t][kk], acc[1][t], 0, 0, 0);
      }
    }
    // epilogue: Q -> T1 [tok][d], K -> T2 [tok][d], V kept in regs
    float vres[2][2][4];
#pragma unroll
    for (int t = 0; t < 2; ++t)
#pragma unroll
      for (int mt = 0; mt < 2; ++mt)
#pragma unroll
        for (int rr = 0; rr < 4; ++rr) {
          const int row = (mt * 16 + quad * 4 + rr) * 40 + t * 16 + l16;
          T1[row] = f2bs((acc[mt][t][rr] + qb6[t]) * SCALE_Q);
          T2[row] = f2bs(acc[mt][2 + t][rr] + qb6[2 + t]);
          vres[t][mt][rr] = acc[mt][4 + t][rr] + qb6[4 + t];
        }

    // ---- attention (wave-local), SWAPPED QK^T ----
    bf16x8 aq[2], bk[2];
#pragma unroll
    for (int t = 0; t < 2; ++t) {
      aq[t] = *reinterpret_cast<const bf16x8*>(&T1[(t * 16 + l16) * 40 + quad * 8]);
      bk[t] = *reinterpret_cast<const bf16x8*>(&T2[(t * 16 + l16) * 40 + quad * 8]);
    }
    // St[nt][mt][rr]: q = mt*16 + l16 (col), k = nt*16 + quad*4 + rr (row)
    floatx4 St[2][2];
#pragma unroll
    for (int nt = 0; nt < 2; ++nt)
#pragma unroll
      for (int mt = 0; mt < 2; ++mt)
        St[nt][mt] = __builtin_amdgcn_mfma_f32_16x16x32_bf16(bk[nt], aq[mt], zero, 0, 0, 0);

#pragma unroll
    for (int mt = 0; mt < 2; ++mt) {
      float v[2][4];
      float mx = -1e30f;
#pragma unroll
      for (int nt = 0; nt < 2; ++nt)
#pragma unroll
        for (int rr = 0; rr < 4; ++rr) {
          const int kidx = nt * 16 + quad * 4 + rr;
          v[nt][rr] = (kidx < 25) ? St[nt][mt][rr] + cmb[mt][nt][rr] : -1e30f;
          mx = fmaxf(mx, v[nt][rr]);
        }
      mx = fmaxf(mx, __shfl_xor(mx, 16));
      mx = fmaxf(mx, __shfl_xor(mx, 32));
      float e[2][4];
      float sm = 0.f;
#pragma unroll
      for (int nt = 0; nt < 2; ++nt)
#pragma unroll
        for (int rr = 0; rr < 4; ++rr) {
          e[nt][rr] = __expf(v[nt][rr] - mx);
          sm += e[nt][rr];
        }
      sm += __shfl_xor(sm, 16);
      sm += __shfl_xor(sm, 32);
      const float inv = 1.f / sm;
      // P[q = mt*16+l16][k = nt*16+quad*4 .. +3] packed (K tile consumed)
#pragma unroll
      for (int nt = 0; nt < 2; ++nt) {
        short4 pk;
        pk.x = f2bs(e[nt][0] * inv);
        pk.y = f2bs(e[nt][1] * inv);
        pk.z = f2bs(e[nt][2] * inv);
        pk.w = f2bs(e[nt][3] * inv);
        *reinterpret_cast<short4*>(&T2[(mt * 16 + l16) * 40 + nt * 16 + quad * 4]) = pk;
      }
    }
    // VT over Q in T1 (Q consumed): [d][tok], packed 4 tokens per store
#pragma unroll
    for (int t = 0; t < 2; ++t)
#pragma unroll
      for (int mt = 0; mt < 2; ++mt) {
        short4 pk;
        pk.x = f2bs(vres[t][mt][0]); pk.y = f2bs(vres[t][mt][1]);
        pk.z = f2bs(vres[t][mt][2]); pk.w = f2bs(vres[t][mt][3]);
        *reinterpret_cast<short4*>(&T1[(t * 16 + l16) * 40 + mt * 16 + quad * 4]) = pk;
      }
    bf16x8 ap[2], bv[2];
#pragma unroll
    for (int t = 0; t < 2; ++t) {
      ap[t] = *reinterpret_cast<const bf16x8*>(&T2[(t * 16 + l16) * 40 + quad * 8]);
      bv[t] = *reinterpret_cast<const bf16x8*>(&T1[(t * 16 + l16) * 40 + quad * 8]);
    }
    floatx4 O[2][2];
#pragma unroll
    for (int mt = 0; mt < 2; ++mt)
#pragma unroll
      for (int nt = 0; nt < 2; ++nt)
        O[mt][nt] = __builtin_amdgcn_mfma_f32_16x16x32_bf16(ap[mt], bv[nt], zero, 0, 0, 0);
    // O over VT in T1: [tok][d_local]
#pragma unroll
    for (int mt = 0; mt < 2; ++mt)
#pragma unroll
      for (int rr = 0; rr < 4; ++rr)
#pragma unroll
        for (int nt = 0; nt < 2; ++nt)
          T1[(mt * 16 + quad * 4 + rr) * 40 + nt * 16 + l16] = f2bs(O[mt][nt][rr]);

    // stage next window into the other XB half (fp32 -> bf16 here; the
    // vmcnt wait for xf* lands HERE, ~a full round after issue)
    if (r < 3) {
      bf16x8 a, b;
      a[0] = f2bs(xf0.x); a[1] = f2bs(xf0.y); a[2] = f2bs(xf0.z); a[3] = f2bs(xf0.w);
      a[4] = f2bs(xf1.x); a[5] = f2bs(xf1.y); a[6] = f2bs(xf1.z); a[7] = f2bs(xf1.w);
      b[0] = f2bs(xf2.x); b[1] = f2bs(xf2.y); b[2] = f2bs(xf2.z); b[3] = f2bs(xf2.w);
      b[4] = f2bs(xf3.x); b[5] = f2bs(xf3.y); b[6] = f2bs(xf3.z); b[7] = f2bs(xf3.w);
      const int off = ((r + 1) & 1) * 512;
      *reinterpret_cast<bf16x8*>(XB + swz(off + ubase) * 8) = a;
      *reinterpret_cast<bf16x8*>(XB + swz(off + ubase + 16) * 8) = b;
    }
    __syncthreads();   // barrier 2: all O tiles ready, XB staged

    // ---- proj: wave h -> out cols [h*32, h*32+32) ----
    floatx4 acc2[2][2];
#pragma unroll
    for (int mt = 0; mt < 2; ++mt)
#pragma unroll
      for (int nt = 0; nt < 2; ++nt) acc2[mt][nt] = zero;
#pragma unroll
    for (int kk = 0; kk < 4; ++kk) {
      const bf16x8 a20 = *reinterpret_cast<const bf16x8*>(
          &TL[kk * 2560 + (l16) * 40 + quad * 8]);
      const bf16x8 a21 = *reinterpret_cast<const bf16x8*>(
          &TL[kk * 2560 + (16 + l16) * 40 + quad * 8]);
#pragma unroll
      for (int nt = 0; nt < 2; ++nt) {
        acc2[0][nt] = __builtin_amdgcn_mfma_f32_16x16x32_bf16(a20, w2f[nt][kk], acc2[0][nt], 0, 0, 0);
        acc2[1][nt] = __builtin_amdgcn_mfma_f32_16x16x32_bf16(a21, w2f[nt][kk], acc2[1][nt], 0, 0, 0);
      }
    }
#pragma unroll
    for (int mt = 0; mt < 2; ++mt)
#pragma unroll
      for (int rr = 0; rr < 4; ++rr) {
        const int m = mt * 16 + quad * 4 + rr;
        if (m < 25) {
#pragma unroll
          for (int nt = 0; nt < 2; ++nt)
            out[((size_t)win * NKEEP + m) * DIM + h * 32 + nt * 16 + l16] =
                acc2[mt][nt][rr] + pbf[nt];
        }
      }
  }
}

extern "C" void kernel_launch(void* const* d_in, const int* in_sizes, int n_in,
                              void* d_out, int out_size, void* d_ws, size_t ws_size,
                              hipStream_t stream) {
  const float* x    = (const float*)d_in[0];
  const float* mask = (const float*)d_in[1];
  const int*   ids  = (const int*)d_in[2];
  const float* qkvw = (const float*)d_in[3];
  const float* qkvb = (const float*)d_in[4];
  const float* pw   = (const float*)d_in[5];
  const float* pb   = (const float*)d_in[6];
  const float* btab = (const float*)d_in[7];
  const int*   rel  = (const int*)d_in[8];

  short* w1s   = (short*)d_ws;                      // 96 KB
  short* w2s   = w1s + (size_t)NW1 * 8;             // 32 KB
  float* combs = (float*)(w2s + (size_t)NW2 * 8);   // 1 MB
  float* out   = (float*)d_out;

  k_prep <<<dim3((NCB + NW1 + NW2) / 256), 256, 0, stream>>>(
      qkvw, pw, mask, ids, rel, btab, w1s, w2s, combs);
  k_fused<<<dim3(B_TOT / 4), 256, 0, stream>>>(
      x, w1s, w2s, qkvb, pb, combs, out);
}